// Round 6
// baseline (462.897 us; speedup 1.0000x reference)
//
#include <hip/hip_runtime.h>
#include <hip/hip_bf16.h>

#define IN_FEATS 602
#define KP 608               // K padded to 19*32
#define N_HIDDEN 256
#define N_CLASSES 41
#define N_SRC0 292864
#define N_DST0 11264
#define N_DST1 1024
#define FAN0 25
#define FAN1 10
#define NBLK_N (N_SRC0 / 128)        // 2288 neigh-gemm blocks
#define NBLK_S (N_DST0 / 128)        // 88 self-gemm blocks

typedef __attribute__((ext_vector_type(4))) float f32x4;
typedef __attribute__((ext_vector_type(8))) short bf16x8;

// round-to-nearest-even f32 -> bf16, packed pair
static __device__ __forceinline__ unsigned pack_bf16x2(float lo, float hi) {
    unsigned a = __float_as_uint(lo);
    unsigned b = __float_as_uint(hi);
    a = (a + 0x7fffu + ((a >> 16) & 1u)) >> 16;
    b = (b + 0x7fffu + ((b >> 16) & 1u)) >> 16;
    return (a & 0xffffu) | (b << 16);
}

// ---------------------------------------------------------------------------
// wprep: W[602][256] f32 -> Wt[256][608] bf16 (transposed, K-major, zero-pad).
// z-dim selects self/neigh.
// ---------------------------------------------------------------------------
__global__ __launch_bounds__(256) void wprep_kernel(
    const float* __restrict__ Ws, const float* __restrict__ Wn,
    __hip_bfloat16* __restrict__ Wst, __hip_bfloat16* __restrict__ Wnt)
{
    const float* W = blockIdx.z ? Wn : Ws;
    __hip_bfloat16* Wt = blockIdx.z ? Wnt : Wst;

    __shared__ float tile[32][33];
    const int k0 = blockIdx.x * 32, n0 = blockIdx.y * 32;
    const int tx = threadIdx.x & 31, ty = threadIdx.x >> 5;   // 32 x 8

    #pragma unroll
    for (int i = 0; i < 4; ++i) {
        const int k = k0 + ty + i * 8;
        const int n = n0 + tx;
        tile[ty + i * 8][tx] = (k < IN_FEATS) ? W[(size_t)k * N_HIDDEN + n] : 0.f;
    }
    __syncthreads();
    #pragma unroll
    for (int i = 0; i < 4; ++i) {
        const int n = n0 + ty + i * 8;
        const int k = k0 + tx;
        Wt[(size_t)n * KP + k] = __float2bfloat16(tile[tx][ty + i * 8]);
    }
}

// ---------------------------------------------------------------------------
// zgemm: z[m][n] = bf16( x[m] @ W )  for W in {Wn0 (all rows), Ws0 (first 11264)}
// M-tile 128, N=256 full, BK=32, 512 threads = 8 waves (2 x 4), wave tile 64x64.
// A staged f32->bf16 in registers (x rows are only 8-B aligned -> float2 loads).
// HBM-bound by design: per-CU stage:MFMA cycles ~10:1.
// ---------------------------------------------------------------------------
__global__ __launch_bounds__(512, 4) void zgemm_kernel(
    const float* __restrict__ x,
    const __hip_bfloat16* __restrict__ Wnt,   // [256][608]
    const __hip_bfloat16* __restrict__ Wst,   // [256][608]
    __hip_bfloat16* __restrict__ zn,          // [292864][256]
    __hip_bfloat16* __restrict__ zs)          // [11264][256]
{
    __shared__ short As[128 * 40];    // 10 KB, row stride 40 bf16 (80 B)
    __shared__ short Bs[256 * 40];    // 20 KB

    const int bb = blockIdx.x;
    const __hip_bfloat16* Wt = (bb < NBLK_N) ? Wnt : Wst;
    __hip_bfloat16* zout      = (bb < NBLK_N) ? zn  : zs;
    const int m0 = ((bb < NBLK_N) ? bb : bb - NBLK_N) * 128;

    const int tid  = threadIdx.x;
    const int lane = tid & 63;
    const int w    = tid >> 6;          // 0..7
    const int wm   = w >> 2;            // 0..1  (row half)
    const int wn   = w & 3;             // 0..3  (col quarter)
    const int r    = lane & 15;
    const int g    = lane >> 4;

    // stage mappings
    const int arow = tid >> 2;          // 0..127
    const int akq  = (tid & 3) * 8;     // k offset 0,8,16,24
    const int brow = tid >> 1;          // 0..255
    const int bkq  = (tid & 1) * 16;    // k offset 0,16

    const float* xrow = x + (size_t)(m0 + arow) * IN_FEATS;

    f32x4 acc[4][4] = {};

    for (int k0 = 0; k0 < KP; k0 += 32) {
        // ---- issue global loads (regs) ----
        float2 av[4];
        #pragma unroll
        for (int i = 0; i < 4; ++i) {
            const int k = k0 + akq + i * 2;
            av[i] = (k < IN_FEATS) ? *(const float2*)&xrow[k] : make_float2(0.f, 0.f);
        }
        const float4 bv0 = *(const float4*)&Wt[(size_t)brow * KP + k0 + bkq];
        const float4 bv1 = *(const float4*)&Wt[(size_t)brow * KP + k0 + bkq + 8];

        __syncthreads();   // previous step's frag reads done

        uint4 ap;
        ap.x = pack_bf16x2(av[0].x, av[0].y);
        ap.y = pack_bf16x2(av[1].x, av[1].y);
        ap.z = pack_bf16x2(av[2].x, av[2].y);
        ap.w = pack_bf16x2(av[3].x, av[3].y);
        *(uint4*)&As[arow * 40 + akq] = ap;
        *(float4*)&Bs[brow * 40 + bkq]     = bv0;
        *(float4*)&Bs[brow * 40 + bkq + 8] = bv1;

        __syncthreads();   // writes visible

        bf16x8 bf[4];
        #pragma unroll
        for (int nf = 0; nf < 4; ++nf)
            bf[nf] = *(const bf16x8*)&Bs[(wn * 64 + nf * 16 + r) * 40 + g * 8];
        #pragma unroll
        for (int mf = 0; mf < 4; ++mf) {
            const bf16x8 af = *(const bf16x8*)&As[(wm * 64 + mf * 16 + r) * 40 + g * 8];
            #pragma unroll
            for (int nf = 0; nf < 4; ++nf)
                acc[mf][nf] = __builtin_amdgcn_mfma_f32_16x16x32_bf16(af, bf[nf], acc[mf][nf], 0, 0, 0);
        }
    }

    // epilogue: col = wn*64 + nf*16 + r, row = wm*64 + mf*16 + g*4 + j (m89 layout)
    #pragma unroll
    for (int mf = 0; mf < 4; ++mf)
        #pragma unroll
        for (int nf = 0; nf < 4; ++nf) {
            const int col = wn * 64 + nf * 16 + r;
            #pragma unroll
            for (int j = 0; j < 4; ++j) {
                const int row = m0 + wm * 64 + mf * 16 + g * 4 + j;
                zout[(size_t)row * N_HIDDEN + col] = __float2bfloat16(acc[mf][nf][j]);
            }
        }
}

// ---------------------------------------------------------------------------
// zfin: h[d] = relu( zs[d] + mean_25 zn[idx0[d]] + b0 )    (f32 out)
// 4 waves per block, one dst per wave; lane covers 4 cols (8 B per row read).
// ---------------------------------------------------------------------------
__global__ __launch_bounds__(256) void zfin_kernel(
    const __hip_bfloat16* __restrict__ zn,
    const __hip_bfloat16* __restrict__ zs,
    const int* __restrict__ idx0,
    const float* __restrict__ b0,
    float* __restrict__ h)
{
    const int w = threadIdx.x >> 6;
    const int lane = threadIdx.x & 63;
    const int d = blockIdx.x * 4 + w;

    __shared__ int sidx[4][FAN0];
    if (lane < FAN0) sidx[w][lane] = idx0[d * FAN0 + lane];
    __syncthreads();

    float s0 = 0.f, s1 = 0.f, s2 = 0.f, s3 = 0.f;
    #pragma unroll
    for (int n = 0; n < FAN0; ++n) {
        const uint2 v = *(const uint2*)&zn[(size_t)sidx[w][n] * N_HIDDEN + lane * 4];
        s0 += __uint_as_float(v.x << 16);
        s1 += __uint_as_float(v.x & 0xffff0000u);
        s2 += __uint_as_float(v.y << 16);
        s3 += __uint_as_float(v.y & 0xffff0000u);
    }
    const uint2 sv = *(const uint2*)&zs[(size_t)d * N_HIDDEN + lane * 4];
    const float4 bv = *(const float4*)&b0[lane * 4];

    float4 o;
    o.x = fmaxf(__uint_as_float(sv.x << 16)          + s0 * (1.0f / FAN0) + bv.x, 0.f);
    o.y = fmaxf(__uint_as_float(sv.x & 0xffff0000u)  + s1 * (1.0f / FAN0) + bv.y, 0.f);
    o.z = fmaxf(__uint_as_float(sv.y << 16)          + s2 * (1.0f / FAN0) + bv.z, 0.f);
    o.w = fmaxf(__uint_as_float(sv.y & 0xffff0000u)  + s3 * (1.0f / FAN0) + bv.w, 0.f);
    *(float4*)&h[(size_t)d * N_HIDDEN + lane * 4] = o;
}

// ---------------------------------------------------------------------------
// tail: out[d] = h[d]@Ws1 + (mean_10 h[idx1])@Wn1 + b1.  4 dsts per block.
// (verified body from R5)
// ---------------------------------------------------------------------------
__global__ __launch_bounds__(256) void tail_kernel(
    const float* __restrict__ h,
    const int* __restrict__ idx1,
    const float* __restrict__ Ws,     // [256][41]
    const float* __restrict__ Wn,     // [256][41]
    const float* __restrict__ b,      // [41]
    float* __restrict__ out)          // [1024][41]
{
    const int w = threadIdx.x >> 6;
    const int lane = threadIdx.x & 63;
    const int d = blockIdx.x * 4 + w;

    __shared__ float hd[4][N_HIDDEN];
    __shared__ float hn[4][N_HIDDEN];
    __shared__ int sidx[4][FAN1];
    if (lane < FAN1) sidx[w][lane] = idx1[d * FAN1 + lane];
    __syncthreads();

    {
        const int k0 = lane * 4;
        const float4 self = *(const float4*)&h[(size_t)d * N_HIDDEN + k0];
        float ax = 0.f, ay = 0.f, az = 0.f, aw = 0.f;
        #pragma unroll
        for (int i = 0; i < FAN1; ++i) {
            const float4 v = *(const float4*)&h[(size_t)sidx[w][i] * N_HIDDEN + k0];
            ax += v.x; ay += v.y; az += v.z; aw += v.w;
        }
        *(float4*)&hd[w][k0] = self;
        hn[w][k0 + 0] = ax * (1.0f / FAN1);
        hn[w][k0 + 1] = ay * (1.0f / FAN1);
        hn[w][k0 + 2] = az * (1.0f / FAN1);
        hn[w][k0 + 3] = aw * (1.0f / FAN1);
    }
    __syncthreads();

    if (lane < N_CLASSES) {
        const int n = lane;
        float a0 = b[n], a1 = 0.f, a2 = 0.f, a3 = 0.f;
        #pragma unroll 4
        for (int k = 0; k < N_HIDDEN; k += 4) {
            a0 += hd[w][k + 0] * Ws[(k + 0) * N_CLASSES + n] + hn[w][k + 0] * Wn[(k + 0) * N_CLASSES + n];
            a1 += hd[w][k + 1] * Ws[(k + 1) * N_CLASSES + n] + hn[w][k + 1] * Wn[(k + 1) * N_CLASSES + n];
            a2 += hd[w][k + 2] * Ws[(k + 2) * N_CLASSES + n] + hn[w][k + 2] * Wn[(k + 2) * N_CLASSES + n];
            a3 += hd[w][k + 3] * Ws[(k + 3) * N_CLASSES + n] + hn[w][k + 3] * Wn[(k + 3) * N_CLASSES + n];
        }
        out[(size_t)d * N_CLASSES + n] = a0 + a1 + a2 + a3;
    }
}

// ---------------------------------------------------------------------------
extern "C" void kernel_launch(void* const* d_in, const int* in_sizes, int n_in,
                              void* d_out, int out_size, void* d_ws, size_t ws_size,
                              hipStream_t stream) {
    const float* x       = (const float*)d_in[0];
    const float* Wself0  = (const float*)d_in[1];
    const float* Wneigh0 = (const float*)d_in[2];
    const float* b0      = (const float*)d_in[3];
    const float* Wself1  = (const float*)d_in[4];
    const float* Wneigh1 = (const float*)d_in[5];
    const float* b1      = (const float*)d_in[6];
    const int*   idx0    = (const int*)d_in[7];
    const int*   idx1    = (const int*)d_in[8];
    float* out = (float*)d_out;

    // ws: zn bf16 [292864*256] (150MB) | zs bf16 [11264*256] | h f32 [11264*256]
    //     | Wst bf16 [256*608] | Wnt bf16 [256*608]     total ~168 MB
    __hip_bfloat16* zn  = (__hip_bfloat16*)d_ws;
    __hip_bfloat16* zs  = zn + (size_t)N_SRC0 * N_HIDDEN;
    float*          h   = (float*)(zs + (size_t)N_DST0 * N_HIDDEN);
    __hip_bfloat16* Wst = (__hip_bfloat16*)(h + (size_t)N_DST0 * N_HIDDEN);
    __hip_bfloat16* Wnt = Wst + (size_t)N_HIDDEN * KP;

    wprep_kernel<<<dim3(KP / 32, N_HIDDEN / 32, 2), 256, 0, stream>>>(Wself0, Wneigh0, Wst, Wnt);
    zgemm_kernel<<<NBLK_N + NBLK_S, 512, 0, stream>>>(x, Wnt, Wst, zn, zs);
    zfin_kernel<<<N_DST0 / 4, 256, 0, stream>>>(zn, zs, idx0, b0, h);
    tail_kernel<<<N_DST1 / 4, 256, 0, stream>>>(h, idx1, Wself1, Wneigh1, b1, out);
}